// Round 9
// baseline (337.500 us; speedup 1.0000x reference)
//
#include <hip/hip_runtime.h>
#include <hip/hip_fp16.h>

#define DCH 64
#define NBSHIFT 8
#define BROWS 256            // nodes per bucket = 1<<NBSHIFT
#define MAXNB 512
#define CAP 8192             // pass-C staging capacity (edges per bucket)
#define CHUNK 4096           // pass-B edges per block

__global__ void zero_i32(int* __restrict__ p, int n) {
    int i = blockIdx.x * blockDim.x + threadIdx.x;
    if (i < n) p[i] = 0;
}

// pass A: global bucket histogram via per-block LDS histograms
__global__ __launch_bounds__(256) void bucket_hist(const int* __restrict__ dst,
                                                   int* __restrict__ counts, int E, int NB) {
    __shared__ int hist[MAXNB];
    for (int i = threadIdx.x; i < NB; i += blockDim.x) hist[i] = 0;
    __syncthreads();
    for (int e = blockIdx.x * blockDim.x + threadIdx.x; e < E; e += gridDim.x * blockDim.x)
        atomicAdd(&hist[dst[e] >> NBSHIFT], 1);
    __syncthreads();
    for (int i = threadIdx.x; i < NB; i += blockDim.x) {
        int c = hist[i];
        if (c) atomicAdd(&counts[i], c);
    }
}

// scan bucket counts -> bases, init global cursors; also rowptr[N]=E
__global__ __launch_bounds__(MAXNB) void bucket_scan(const int* __restrict__ counts,
        int* __restrict__ bases, int* __restrict__ cursor, int* __restrict__ rowptr,
        int NB, int N, int E) {
    __shared__ int lds[MAXNB];
    int t = threadIdx.x;
    int v = (t < NB) ? counts[t] : 0;
    lds[t] = v;
    __syncthreads();
    for (int off = 1; off < MAXNB; off <<= 1) {
        int add = (t >= off) ? lds[t - off] : 0;
        __syncthreads();
        lds[t] += add;
        __syncthreads();
    }
    if (t < NB) { int b = lds[t] - v; bases[t] = b; cursor[t] = b; }
    if (t == 0) rowptr[N] = E;
}

// pass B: scatter edges into bucket-contiguous regions as packed (dstLow8<<24)|src
__global__ __launch_bounds__(256) void bucket_scatter(const int* __restrict__ src,
        const int* __restrict__ dst, int* __restrict__ cursor,
        unsigned int* __restrict__ tmp, int E, int NB) {
    __shared__ int hist[MAXNB];
    __shared__ int res[MAXNB];
    const int base_e = blockIdx.x * CHUNK;
    const int nloc = min(CHUNK, E - base_e);
    for (int i = threadIdx.x; i < NB; i += blockDim.x) hist[i] = 0;
    __syncthreads();
    for (int i = threadIdx.x; i < nloc; i += blockDim.x)
        atomicAdd(&hist[dst[base_e + i] >> NBSHIFT], 1);
    __syncthreads();
    for (int i = threadIdx.x; i < NB; i += blockDim.x) {
        int c = hist[i];
        res[i] = c ? atomicAdd(&cursor[i], c) : 0;
        hist[i] = 0;                       // reuse as local cursor
    }
    __syncthreads();
    for (int i = threadIdx.x; i < nloc; i += blockDim.x) {
        int d = dst[base_e + i];
        int b = d >> NBSHIFT;
        int r = atomicAdd(&hist[b], 1);
        unsigned int packed = ((unsigned int)(d & (BROWS - 1)) << 24) |
                              (unsigned int)src[base_e + i];
        tmp[res[b] + r] = packed;
    }
}

// pass C: one block per bucket -> rowptr, dinv, coalesced srcs
__global__ __launch_bounds__(BROWS) void bucket_to_csr(
        const unsigned int* __restrict__ tmp, const int* __restrict__ bases,
        const int* __restrict__ counts, int* __restrict__ rowptr,
        int* __restrict__ srcs, float* __restrict__ dinv, int N) {
    __shared__ int hist[BROWS];
    __shared__ int off[BROWS];
    __shared__ int cur[BROWS];
    __shared__ int stage[CAP];
    const int b = blockIdx.x;
    const int base = bases[b], count = counts[b];
    const int t = threadIdx.x;
    hist[t] = 0;
    __syncthreads();
    for (int i = t; i < count; i += BROWS)
        atomicAdd(&hist[tmp[base + i] >> 24], 1);
    __syncthreads();
    int v = hist[t];
    off[t] = v;
    __syncthreads();
    for (int o = 1; o < BROWS; o <<= 1) {
        int add = (t >= o) ? off[t - o] : 0;
        __syncthreads();
        off[t] += add;
        __syncthreads();
    }
    int excl = off[t] - v;
    cur[t] = excl;
    int node = (b << NBSHIFT) + t;
    if (node <= N) rowptr[node] = base + excl;     // node==N lands in last bucket -> rowptr[N]=E
    if (node < N)  dinv[node] = rsqrtf((float)v + 1.0f);
    __syncthreads();
    const bool st = (count <= CAP);
    for (int i = t; i < count; i += BROWS) {
        unsigned int p = tmp[base + i];
        int low = p >> 24;
        int s = (int)(p & 0xFFFFFFu);
        int pos = atomicAdd(&cur[low], 1);
        if (st) stage[pos] = s;
        else    srcs[base + pos] = s;              // overflow fallback (uncoalesced, rare)
    }
    __syncthreads();
    if (st)
        for (int i = t; i < count; i += BROWS) srcs[base + i] = stage[i];
}

// register-tiled Hs[r][c] = half( (A[64xK] * W[KxC]) * dinv[r] ); 64x64 tile, 4x4/thread
// launch_bounds(256,4): cap 128 VGPR -> 4 blocks/CU. float4 LDS staging, pad 68.
__global__ __launch_bounds__(256, 4) void gemm64(const float* __restrict__ A,
        const float* __restrict__ W, const float* __restrict__ dinv,
        __half* __restrict__ H, int nrows) {
    __shared__ float Wl[64 * 64];      // [k][c]
    __shared__ float Al[64 * 68];      // [r][k], pad 68: f4-aligned, bank-stride 4
    #pragma unroll
    for (int j = 0; j < 4; ++j) {
        int idx = (int)threadIdx.x + j * 256;          // 0..1023
        float4 w = ((const float4*)W)[idx];
        int k = idx >> 4, c = (idx & 15) * 4;
        *(float4*)&Wl[k * 64 + c] = w;
    }
    const int tx = threadIdx.x & 15;
    const int ty = threadIdx.x >> 4;
    const int c0 = tx * 4, r0 = ty * 4;
    const int ntiles = (nrows + 63) >> 6;
    for (int tile = blockIdx.x; tile < ntiles; tile += gridDim.x) {
        const int rowbase = tile << 6;
        const int rmax = min(64, nrows - rowbase);
        __syncthreads();
        #pragma unroll
        for (int j = 0; j < 4; ++j) {
            int idx = (int)threadIdx.x + j * 256;
            int r = idx >> 4, k = (idx & 15) * 4;
            float4 a = (r < rmax) ? *(const float4*)(A + (size_t)(rowbase + r) * 64 + k)
                                  : make_float4(0.f, 0.f, 0.f, 0.f);
            *(float4*)&Al[r * 68 + k] = a;
        }
        __syncthreads();
        float acc[4][4] = {};
        #pragma unroll 8
        for (int k = 0; k < 64; ++k) {
            float4 wv = *(const float4*)&Wl[k * 64 + c0];
            float a0 = Al[(r0 + 0) * 68 + k];
            float a1 = Al[(r0 + 1) * 68 + k];
            float a2 = Al[(r0 + 2) * 68 + k];
            float a3 = Al[(r0 + 3) * 68 + k];
            acc[0][0] += a0 * wv.x; acc[0][1] += a0 * wv.y; acc[0][2] += a0 * wv.z; acc[0][3] += a0 * wv.w;
            acc[1][0] += a1 * wv.x; acc[1][1] += a1 * wv.y; acc[1][2] += a1 * wv.z; acc[1][3] += a1 * wv.w;
            acc[2][0] += a2 * wv.x; acc[2][1] += a2 * wv.y; acc[2][2] += a2 * wv.z; acc[2][3] += a2 * wv.w;
            acc[3][0] += a3 * wv.x; acc[3][1] += a3 * wv.y; acc[3][2] += a3 * wv.z; acc[3][3] += a3 * wv.w;
        }
        #pragma unroll
        for (int i = 0; i < 4; ++i) {
            int r = r0 + i;
            if (r < rmax) {
                float s = dinv[rowbase + r];
                __half2* ph = (__half2*)(H + (size_t)(rowbase + r) * 64 + c0);
                ph[0] = __floats2half2_rn(acc[i][0] * s, acc[i][1] * s);
                ph[1] = __floats2half2_rn(acc[i][2] * s, acc[i][3] * s);
            }
        }
    }
}

__device__ __forceinline__ void accum8(float acc[8], float4 v) {
    const __half2* hp = (const __half2*)&v;
    #pragma unroll
    for (int j = 0; j < 4; ++j) {
        float2 f = __half22float2(hp[j]);
        acc[2 * j]     += f.x;
        acc[2 * j + 1] += f.y;
    }
}

// one wave per (dst node, 64B row-half). lane = g*4+q: g = edge subgroup
// (16 edges per load-instr ~ avg degree), q = 16B chunk within the half.
// Dual-load: 32 edges in flight covers deg<=32 (99.9%) in one round-trip.
// hs rows pre-scaled by dinv[src], fp16.
// out[d][c] = act( (sum_{s in N(d) ∪ {d}} hs[s][c]) * dinv[d] + b[c] )
__global__ __launch_bounds__(256) void aggregate(
    const __half* __restrict__ hs, const int* __restrict__ rowptr,
    const int* __restrict__ srcs, const float* __restrict__ dinv,
    const float* __restrict__ b, float* __restrict__ out, int n, int do_relu)
{
    int gwave = (blockIdx.x * blockDim.x + threadIdx.x) >> 6;
    int wid   = gwave >> 1;          // node
    int half  = gwave & 1;           // which 64B half of the 128B row
    if (wid >= n) return;
    int lane = threadIdx.x & 63;
    const int g = lane >> 2;         // 0..15 edge group
    const int q = lane & 3;          // 0..3  16B chunk
    const char* hb = (const char*)hs + half * 64 + q * 16;
    int beg = rowptr[wid], end = rowptr[wid + 1];
    float acc[8] = {}, acc2[8] = {};
    if (g == 15) accum8(acc, *(const float4*)(hb + ((size_t)wid << 7)));  // self-loop
    int e = beg + g;
    for (; e + 16 < end; e += 32) {              // 2x16 gathers in flight
        int s0 = srcs[e];
        int s1 = srcs[e + 16];
        float4 v0 = *(const float4*)(hb + ((size_t)s0 << 7));
        float4 v1 = *(const float4*)(hb + ((size_t)s1 << 7));
        accum8(acc, v0);
        accum8(acc2, v1);
    }
    if (e < end) accum8(acc, *(const float4*)(hb + ((size_t)srcs[e] << 7)));
    #pragma unroll
    for (int j = 0; j < 8; ++j) {
        float a = acc[j] + acc2[j];
        a += __shfl_xor(a, 4);
        a += __shfl_xor(a, 8);
        a += __shfl_xor(a, 16);
        a += __shfl_xor(a, 32);
        acc[j] = a;
    }
    if (g == 0) {
        float dd = dinv[wid];
        int c = half * 32 + q * 8;
        float o[8];
        #pragma unroll
        for (int j = 0; j < 8; ++j) {
            float v = acc[j] * dd + b[c + j];
            o[j] = do_relu ? fmaxf(v, 0.f) : v;
        }
        float4* po = (float4*)(out + (size_t)wid * DCH + c);
        po[0] = make_float4(o[0], o[1], o[2], o[3]);
        po[1] = make_float4(o[4], o[5], o[6], o[7]);
    }
}

extern "C" void kernel_launch(void* const* d_in, const int* in_sizes, int n_in,
                              void* d_out, int out_size, void* d_ws, size_t ws_size,
                              hipStream_t stream) {
    const float* x  = (const float*)d_in[0];
    const int*   ei = (const int*)d_in[1];
    const float* W1 = (const float*)d_in[2];
    const float* b1 = (const float*)d_in[3];
    const float* W2 = (const float*)d_in[4];
    const float* b2 = (const float*)d_in[5];
    const float* W3 = (const float*)d_in[6];
    const float* b3 = (const float*)d_in[7];

    const int N = in_sizes[0] / DCH;
    const int E = in_sizes[1] / 2;
    const int* src = ei;
    const int* dst = ei + E;
    const int NB = (N + BROWS - 1) >> NBSHIFT;     // 391

    char* ws = (char*)d_ws;
    size_t off = 0;
    auto alloc = [&](size_t bytes) { void* p = ws + off; off = (off + bytes + 255) & ~(size_t)255; return p; };
    int*    counts = (int*)   alloc((size_t)MAXNB * 4);
    int*    bases  = (int*)   alloc((size_t)MAXNB * 4);
    int*    cursor = (int*)   alloc((size_t)MAXNB * 4);
    int*    rowptr = (int*)   alloc(((size_t)N + 1) * 4);
    int*    srcs   = (int*)   alloc((size_t)E * 4);
    float*  dinv   = (float*) alloc((size_t)N * 4);
    __half* hs     = (__half*)alloc((size_t)N * DCH * 2);
    float*  agg    = (float*) alloc((size_t)N * DCH * 4);
    unsigned int* tmp = (unsigned int*)hs;         // alias: tmp dead before first gemm writes hs
    float* out = (float*)d_out;

    const int T = 256;
    const int gAG  = ((size_t)N * 2 * 64 + T - 1) / T;   // 2 waves per node
    const int gGM  = (N + 63) / 64;                // one block per 64-row tile
    const int nchk = (E + CHUNK - 1) / CHUNK;

    // ---- CSR build (counting sort by dst) ----
    zero_i32<<<(NB + T - 1) / T, T, 0, stream>>>(counts, NB);
    bucket_hist<<<256, T, 0, stream>>>(dst, counts, E, NB);
    bucket_scan<<<1, MAXNB, 0, stream>>>(counts, bases, cursor, rowptr, NB, N, E);
    bucket_scatter<<<nchk, T, 0, stream>>>(src, dst, cursor, tmp, E, NB);
    bucket_to_csr<<<NB, BROWS, 0, stream>>>(tmp, bases, counts, rowptr, srcs, dinv, N);

    // ---- layer 1: x -> agg ----
    gemm64<<<gGM, T, 0, stream>>>(x, W1, dinv, hs, N);
    aggregate<<<gAG, T, 0, stream>>>(hs, rowptr, srcs, dinv, b1, agg, N, 1);

    // ---- layer 2: agg -> agg ----
    gemm64<<<gGM, T, 0, stream>>>(agg, W2, dinv, hs, N);
    aggregate<<<gAG, T, 0, stream>>>(hs, rowptr, srcs, dinv, b2, agg, N, 1);

    // ---- layer 3: agg -> d_out ----
    gemm64<<<gGM, T, 0, stream>>>(agg, W3, dinv, hs, N);
    aggregate<<<gAG, T, 0, stream>>>(hs, rowptr, srcs, dinv, b3, out, N, 0);
}

// Round 10
// 239.952 us; speedup vs baseline: 1.4065x; 1.4065x over previous
//
#include <hip/hip_runtime.h>
#include <hip/hip_fp16.h>

#define DCH 64
#define NBSHIFT 8
#define BROWS 256            // nodes per bucket = 1<<NBSHIFT
#define MAXNB 512
#define CAP 8192             // pass-C staging capacity (edges per bucket)
#define CHUNK 4096           // pass-B edges per block

__global__ void zero_i32(int* __restrict__ p, int n) {
    int i = blockIdx.x * blockDim.x + threadIdx.x;
    if (i < n) p[i] = 0;
}

// pass A: global bucket histogram via per-block LDS histograms
__global__ __launch_bounds__(256) void bucket_hist(const int* __restrict__ dst,
                                                   int* __restrict__ counts, int E, int NB) {
    __shared__ int hist[MAXNB];
    for (int i = threadIdx.x; i < NB; i += blockDim.x) hist[i] = 0;
    __syncthreads();
    for (int e = blockIdx.x * blockDim.x + threadIdx.x; e < E; e += gridDim.x * blockDim.x)
        atomicAdd(&hist[dst[e] >> NBSHIFT], 1);
    __syncthreads();
    for (int i = threadIdx.x; i < NB; i += blockDim.x) {
        int c = hist[i];
        if (c) atomicAdd(&counts[i], c);
    }
}

// scan bucket counts -> bases, init global cursors; also rowptr[N]=E
__global__ __launch_bounds__(MAXNB) void bucket_scan(const int* __restrict__ counts,
        int* __restrict__ bases, int* __restrict__ cursor, int* __restrict__ rowptr,
        int NB, int N, int E) {
    __shared__ int lds[MAXNB];
    int t = threadIdx.x;
    int v = (t < NB) ? counts[t] : 0;
    lds[t] = v;
    __syncthreads();
    for (int off = 1; off < MAXNB; off <<= 1) {
        int add = (t >= off) ? lds[t - off] : 0;
        __syncthreads();
        lds[t] += add;
        __syncthreads();
    }
    if (t < NB) { int b = lds[t] - v; bases[t] = b; cursor[t] = b; }
    if (t == 0) rowptr[N] = E;
}

// pass B: scatter edges into bucket-contiguous regions as packed (dstLow8<<24)|src
__global__ __launch_bounds__(256) void bucket_scatter(const int* __restrict__ src,
        const int* __restrict__ dst, int* __restrict__ cursor,
        unsigned int* __restrict__ tmp, int E, int NB) {
    __shared__ int hist[MAXNB];
    __shared__ int res[MAXNB];
    const int base_e = blockIdx.x * CHUNK;
    const int nloc = min(CHUNK, E - base_e);
    for (int i = threadIdx.x; i < NB; i += blockDim.x) hist[i] = 0;
    __syncthreads();
    for (int i = threadIdx.x; i < nloc; i += blockDim.x)
        atomicAdd(&hist[dst[base_e + i] >> NBSHIFT], 1);
    __syncthreads();
    for (int i = threadIdx.x; i < NB; i += blockDim.x) {
        int c = hist[i];
        res[i] = c ? atomicAdd(&cursor[i], c) : 0;
        hist[i] = 0;                       // reuse as local cursor
    }
    __syncthreads();
    for (int i = threadIdx.x; i < nloc; i += blockDim.x) {
        int d = dst[base_e + i];
        int b = d >> NBSHIFT;
        int r = atomicAdd(&hist[b], 1);
        unsigned int packed = ((unsigned int)(d & (BROWS - 1)) << 24) |
                              (unsigned int)src[base_e + i];
        tmp[res[b] + r] = packed;
    }
}

// pass C: one block per bucket -> rowptr, dinv, coalesced srcs
__global__ __launch_bounds__(BROWS) void bucket_to_csr(
        const unsigned int* __restrict__ tmp, const int* __restrict__ bases,
        const int* __restrict__ counts, int* __restrict__ rowptr,
        int* __restrict__ srcs, float* __restrict__ dinv, int N) {
    __shared__ int hist[BROWS];
    __shared__ int off[BROWS];
    __shared__ int cur[BROWS];
    __shared__ int stage[CAP];
    const int b = blockIdx.x;
    const int base = bases[b], count = counts[b];
    const int t = threadIdx.x;
    hist[t] = 0;
    __syncthreads();
    for (int i = t; i < count; i += BROWS)
        atomicAdd(&hist[tmp[base + i] >> 24], 1);
    __syncthreads();
    int v = hist[t];
    off[t] = v;
    __syncthreads();
    for (int o = 1; o < BROWS; o <<= 1) {
        int add = (t >= o) ? off[t - o] : 0;
        __syncthreads();
        off[t] += add;
        __syncthreads();
    }
    int excl = off[t] - v;
    cur[t] = excl;
    int node = (b << NBSHIFT) + t;
    if (node <= N) rowptr[node] = base + excl;     // node==N lands in last bucket -> rowptr[N]=E
    if (node < N)  dinv[node] = rsqrtf((float)v + 1.0f);
    __syncthreads();
    const bool st = (count <= CAP);
    for (int i = t; i < count; i += BROWS) {
        unsigned int p = tmp[base + i];
        int low = p >> 24;
        int s = (int)(p & 0xFFFFFFu);
        int pos = atomicAdd(&cur[low], 1);
        if (st) stage[pos] = s;
        else    srcs[base + pos] = s;              // overflow fallback (uncoalesced, rare)
    }
    __syncthreads();
    if (st)
        for (int i = t; i < count; i += BROWS) srcs[base + i] = stage[i];
}

// register-tiled Hs[r][c] = half( (A[64xK] * W[KxC]) * dinv[r] ); 64x64 tile, 4x4/thread
// launch_bounds(256,4): cap 128 VGPR -> 4 blocks/CU. float4 LDS staging, pad 68.
__global__ __launch_bounds__(256, 4) void gemm64(const float* __restrict__ A,
        const float* __restrict__ W, const float* __restrict__ dinv,
        __half* __restrict__ H, int nrows) {
    __shared__ float Wl[64 * 64];      // [k][c]
    __shared__ float Al[64 * 68];      // [r][k], pad 68: f4-aligned, bank-stride 4
    #pragma unroll
    for (int j = 0; j < 4; ++j) {
        int idx = (int)threadIdx.x + j * 256;          // 0..1023
        float4 w = ((const float4*)W)[idx];
        int k = idx >> 4, c = (idx & 15) * 4;
        *(float4*)&Wl[k * 64 + c] = w;
    }
    const int tx = threadIdx.x & 15;
    const int ty = threadIdx.x >> 4;
    const int c0 = tx * 4, r0 = ty * 4;
    const int ntiles = (nrows + 63) >> 6;
    for (int tile = blockIdx.x; tile < ntiles; tile += gridDim.x) {
        const int rowbase = tile << 6;
        const int rmax = min(64, nrows - rowbase);
        __syncthreads();
        #pragma unroll
        for (int j = 0; j < 4; ++j) {
            int idx = (int)threadIdx.x + j * 256;
            int r = idx >> 4, k = (idx & 15) * 4;
            float4 a = (r < rmax) ? *(const float4*)(A + (size_t)(rowbase + r) * 64 + k)
                                  : make_float4(0.f, 0.f, 0.f, 0.f);
            *(float4*)&Al[r * 68 + k] = a;
        }
        __syncthreads();
        float acc[4][4] = {};
        #pragma unroll 8
        for (int k = 0; k < 64; ++k) {
            float4 wv = *(const float4*)&Wl[k * 64 + c0];
            float a0 = Al[(r0 + 0) * 68 + k];
            float a1 = Al[(r0 + 1) * 68 + k];
            float a2 = Al[(r0 + 2) * 68 + k];
            float a3 = Al[(r0 + 3) * 68 + k];
            acc[0][0] += a0 * wv.x; acc[0][1] += a0 * wv.y; acc[0][2] += a0 * wv.z; acc[0][3] += a0 * wv.w;
            acc[1][0] += a1 * wv.x; acc[1][1] += a1 * wv.y; acc[1][2] += a1 * wv.z; acc[1][3] += a1 * wv.w;
            acc[2][0] += a2 * wv.x; acc[2][1] += a2 * wv.y; acc[2][2] += a2 * wv.z; acc[2][3] += a2 * wv.w;
            acc[3][0] += a3 * wv.x; acc[3][1] += a3 * wv.y; acc[3][2] += a3 * wv.z; acc[3][3] += a3 * wv.w;
        }
        #pragma unroll
        for (int i = 0; i < 4; ++i) {
            int r = r0 + i;
            if (r < rmax) {
                float s = dinv[rowbase + r];
                __half2* ph = (__half2*)(H + (size_t)(rowbase + r) * 64 + c0);
                ph[0] = __floats2half2_rn(acc[i][0] * s, acc[i][1] * s);
                ph[1] = __floats2half2_rn(acc[i][2] * s, acc[i][3] * s);
            }
        }
    }
}

__device__ __forceinline__ void accumh(__half2 acc[4], float4 v) {
    const __half2* hp = (const __half2*)&v;
    #pragma unroll
    for (int j = 0; j < 4; ++j) acc[j] = __hadd2(acc[j], hp[j]);
}

__device__ __forceinline__ float4 row16(const __half* __restrict__ hs, int s, int q) {
    return *(const float4*)((const char*)hs + ((size_t)s << 7) + (q << 4));
}

// one wave per dst node. lane = g*8+q: g = edge subgroup (8 edges/load-instr),
// q = channel oct (half8 = 16B). hs rows pre-scaled by dinv[src], fp16.
// Inner loop: packed fp16 accumulation (v_pk_add_f16, 4 ops/chunk vs 12) with
// dual loads (2 gathers in flight). fp32 only at the wave-level reduce.
// out[d][c] = act( (sum_{s in N(d) ∪ {d}} hs[s][c]) * dinv[d] + b[c] )
__global__ __launch_bounds__(256) void aggregate(
    const __half* __restrict__ hs, const int* __restrict__ rowptr,
    const int* __restrict__ srcs, const float* __restrict__ dinv,
    const float* __restrict__ b, float* __restrict__ out, int n, int do_relu)
{
    int wid  = (blockIdx.x * blockDim.x + threadIdx.x) >> 6;
    int lane = threadIdx.x & 63;
    if (wid >= n) return;
    const int g = lane >> 3;       // 0..7
    const int q = lane & 7;        // 0..7
    int beg = rowptr[wid], end = rowptr[wid + 1];
    __half2 zero = __float2half2_rn(0.f);
    __half2 acch[4]  = {zero, zero, zero, zero};
    __half2 acch2[4] = {zero, zero, zero, zero};
    if (g == 7) accumh(acch, row16(hs, wid, q));    // self-loop on tail group
    int e = beg + g;
    for (; e + 8 < end; e += 16) {                  // 2 gathers in flight
        int s0 = srcs[e];
        int s1 = srcs[e + 8];
        float4 v0 = row16(hs, s0, q);
        float4 v1 = row16(hs, s1, q);
        accumh(acch, v0);
        accumh(acch2, v1);
    }
    if (e < end) accumh(acch, row16(hs, srcs[e], q));
    float acc[8];
    #pragma unroll
    for (int j = 0; j < 4; ++j) {
        float2 f0 = __half22float2(acch[j]);
        float2 f1 = __half22float2(acch2[j]);
        acc[2 * j]     = f0.x + f1.x;
        acc[2 * j + 1] = f0.y + f1.y;
    }
    #pragma unroll
    for (int j = 0; j < 8; ++j) {
        float a = acc[j];
        a += __shfl_xor(a, 8);
        a += __shfl_xor(a, 16);
        a += __shfl_xor(a, 32);
        acc[j] = a;
    }
    if (g == 0) {
        float dd = dinv[wid];
        float o[8];
        #pragma unroll
        for (int j = 0; j < 8; ++j) {
            float v = acc[j] * dd + b[q * 8 + j];
            o[j] = do_relu ? fmaxf(v, 0.f) : v;
        }
        float4* po = (float4*)(out + (size_t)wid * DCH + q * 8);
        po[0] = make_float4(o[0], o[1], o[2], o[3]);
        po[1] = make_float4(o[4], o[5], o[6], o[7]);
    }
}

extern "C" void kernel_launch(void* const* d_in, const int* in_sizes, int n_in,
                              void* d_out, int out_size, void* d_ws, size_t ws_size,
                              hipStream_t stream) {
    const float* x  = (const float*)d_in[0];
    const int*   ei = (const int*)d_in[1];
    const float* W1 = (const float*)d_in[2];
    const float* b1 = (const float*)d_in[3];
    const float* W2 = (const float*)d_in[4];
    const float* b2 = (const float*)d_in[5];
    const float* W3 = (const float*)d_in[6];
    const float* b3 = (const float*)d_in[7];

    const int N = in_sizes[0] / DCH;
    const int E = in_sizes[1] / 2;
    const int* src = ei;
    const int* dst = ei + E;
    const int NB = (N + BROWS - 1) >> NBSHIFT;     // 391

    char* ws = (char*)d_ws;
    size_t off = 0;
    auto alloc = [&](size_t bytes) { void* p = ws + off; off = (off + bytes + 255) & ~(size_t)255; return p; };
    int*    counts = (int*)   alloc((size_t)MAXNB * 4);
    int*    bases  = (int*)   alloc((size_t)MAXNB * 4);
    int*    cursor = (int*)   alloc((size_t)MAXNB * 4);
    int*    rowptr = (int*)   alloc(((size_t)N + 1) * 4);
    int*    srcs   = (int*)   alloc((size_t)E * 4);
    float*  dinv   = (float*) alloc((size_t)N * 4);
    __half* hs     = (__half*)alloc((size_t)N * DCH * 2);
    float*  agg    = (float*) alloc((size_t)N * DCH * 4);
    unsigned int* tmp = (unsigned int*)hs;         // alias: tmp dead before first gemm writes hs
    float* out = (float*)d_out;

    const int T = 256;
    const int gAG  = (N * DCH + T - 1) / T;        // one 64-lane wave per node
    const int gGM  = (N + 63) / 64;                // one block per 64-row tile
    const int nchk = (E + CHUNK - 1) / CHUNK;

    // ---- CSR build (counting sort by dst) ----
    zero_i32<<<(NB + T - 1) / T, T, 0, stream>>>(counts, NB);
    bucket_hist<<<256, T, 0, stream>>>(dst, counts, E, NB);
    bucket_scan<<<1, MAXNB, 0, stream>>>(counts, bases, cursor, rowptr, NB, N, E);
    bucket_scatter<<<nchk, T, 0, stream>>>(src, dst, cursor, tmp, E, NB);
    bucket_to_csr<<<NB, BROWS, 0, stream>>>(tmp, bases, counts, rowptr, srcs, dinv, N);

    // ---- layer 1: x -> agg ----
    gemm64<<<gGM, T, 0, stream>>>(x, W1, dinv, hs, N);
    aggregate<<<gAG, T, 0, stream>>>(hs, rowptr, srcs, dinv, b1, agg, N, 1);

    // ---- layer 2: agg -> agg ----
    gemm64<<<gGM, T, 0, stream>>>(agg, W2, dinv, hs, N);
    aggregate<<<gAG, T, 0, stream>>>(hs, rowptr, srcs, dinv, b2, agg, N, 1);

    // ---- layer 3: agg -> d_out ----
    gemm64<<<gGM, T, 0, stream>>>(agg, W3, dinv, hs, N);
    aggregate<<<gAG, T, 0, stream>>>(hs, rowptr, srcs, dinv, b3, out, N, 0);
}